// Round 20
// baseline (40.738 us; speedup 1.0000x reference)
//
#include <hip/hip_runtime.h>
#include <math.h>

#define BATCH 512
#define HH 224
#define WW 224
#define NPIX (HH * WW)
#define NL 3
#define EPSV 1e-5f
#define GROUPS 8             // strips per image (one per WAVE), 28 rows each

typedef float v2f __attribute__((ext_vector_type(2)));
#define PK2(s) ((v2f){(s), (s)})

// ---------------- Kernel 1: conv3x3(1->4) + relu + partial sums ----------------
// R18 pipeline, repacked: PIXEL pairs in v2f lanes, scalar SGPR weights.
// R19 post-mortem: profiled VALU-active (18us) is ~2x the pk_fma count (7us)
// -> suspect PK2(input) splats materialize as v_mov pairs (arbitrary-reg
// operands can't op_sel-fold). Fix: make the splat side the WAVE-UNIFORM
// weight (SGPR source broadcasts free in VOP3P); inputs enter as natural
// pairs EP[row][d]={R[d],R[d+1]} built once per row (5 pairs/row).
// acc[c][q] over pixel pairs q={01,23}; relu still packed per-pixel-pair.
// Same 288 pk_fma/group; splat movs gone. Structure/fences/lessons as R18.
__global__ __launch_bounds__(256) void conv_pool_k(
    const float* __restrict__ x, const float* __restrict__ cw,
    float* __restrict__ part)
{
  const int tid = threadIdx.x;
  const int wv = tid >> 6;
  const int lane = tid & 63;
  const int W = blockIdx.x * 4 + wv;   // global wave id
  const int b = W >> 3;                // image
  const int s = W & 7;                 // strip
  const int base = s * 28;             // first output row of strip
  const int colc = (lane < 56 ? lane : 55) * 4;  // clamped col
  const float* __restrict__ img = x + (size_t)b * NPIX;

  // scalar weights: uniform address -> s_load -> SGPRs (free VOP3P broadcast)
  float Ks[4][9];
#pragma unroll
  for (int o = 0; o < 4; ++o)
#pragma unroll
    for (int k = 0; k < 9; ++k) Ks[o][k] = cw[o * 9 + k];

  auto ldrow = [&](int ar) -> float4 {
    int rc = ar < 0 ? 0 : (ar > HH - 1 ? HH - 1 : ar);
    return *reinterpret_cast<const float4*>(img + (size_t)rc * WW + colc);
  };
  auto expand = [&](const float4& t, float (&R)[6]) {
    float lft = __shfl_up(t.w, 1);
    R[0] = (lane == 0) ? 0.f : lft;     // image left edge
    float rgt = __shfl_down(t.x, 1);
    R[5] = (lane == 55) ? 0.f : rgt;    // image right edge (lane56 dups lane55)
    R[1] = t.x; R[2] = t.y; R[3] = t.z; R[4] = t.w;
  };
  // EP[d] = {R[d], R[d+1]}, d=0..4; pixel p uses EP[p+dk] for tap col dk
  auto mkpairs = [&](const float (&R)[6], v2f (&P)[5]) {
#pragma unroll
    for (int d = 0; d < 5; ++d) P[d] = (v2f){R[d], R[d + 1]};
  };

  // prologue: window rows base-1 .. base+4 as pair-form EP[0..5]
  v2f EP[6][5];
  {
    float4 rv[6];
#pragma unroll
    for (int k = 0; k < 6; ++k) rv[k] = ldrow(base - 1 + k);
    if (s == 0) rv[0] = make_float4(0.f, 0.f, 0.f, 0.f);  // row -1
#pragma unroll
    for (int k = 0; k < 6; ++k) {
      float R[6];
      expand(rv[k], R);
      mkpairs(R, EP[k]);
    }
  }

  v2f acc[4][2];
#pragma unroll
  for (int c = 0; c < 4; ++c) { acc[c][0] = (v2f){0.f, 0.f}; acc[c][1] = (v2f){0.f, 0.f}; }
  const v2f vzero = {0.f, 0.f};

#pragma unroll
  for (int j = 0; j < 7; ++j) {        // 7 groups of 4 output rows
    // ---- issue next group's loads (rows base+4j+5 .. +8) ----
    float4 nv[4];
    if (j < 6) {
#pragma unroll
      for (int k = 0; k < 4; ++k) nv[k] = ldrow(base + 4 * j + 5 + k);
    }
    __builtin_amdgcn_sched_barrier(0);  // loads may not sink into compute

    // ---- compute group j: pk_fma(EP, splat(SGPR weight)) ----
#pragma unroll
    for (int i = 0; i < 4; ++i) {      // output row base+4j+i
#pragma unroll
      for (int c = 0; c < 4; ++c) {
        // pixel pair (0,1): taps EP[row][0..2]
        v2f t = EP[i][0] * PK2(Ks[c][0]);
        t = __builtin_elementwise_fma(EP[i][1],     PK2(Ks[c][1]), t);
        t = __builtin_elementwise_fma(EP[i][2],     PK2(Ks[c][2]), t);
        t = __builtin_elementwise_fma(EP[i + 1][0], PK2(Ks[c][3]), t);
        t = __builtin_elementwise_fma(EP[i + 1][1], PK2(Ks[c][4]), t);
        t = __builtin_elementwise_fma(EP[i + 1][2], PK2(Ks[c][5]), t);
        t = __builtin_elementwise_fma(EP[i + 2][0], PK2(Ks[c][6]), t);
        t = __builtin_elementwise_fma(EP[i + 2][1], PK2(Ks[c][7]), t);
        t = __builtin_elementwise_fma(EP[i + 2][2], PK2(Ks[c][8]), t);
        acc[c][0] += __builtin_elementwise_max(t, vzero);
        // pixel pair (2,3): taps EP[row][2..4]
        v2f u = EP[i][2] * PK2(Ks[c][0]);
        u = __builtin_elementwise_fma(EP[i][3],     PK2(Ks[c][1]), u);
        u = __builtin_elementwise_fma(EP[i][4],     PK2(Ks[c][2]), u);
        u = __builtin_elementwise_fma(EP[i + 1][2], PK2(Ks[c][3]), u);
        u = __builtin_elementwise_fma(EP[i + 1][3], PK2(Ks[c][4]), u);
        u = __builtin_elementwise_fma(EP[i + 1][4], PK2(Ks[c][5]), u);
        u = __builtin_elementwise_fma(EP[i + 2][2], PK2(Ks[c][6]), u);
        u = __builtin_elementwise_fma(EP[i + 2][3], PK2(Ks[c][7]), u);
        u = __builtin_elementwise_fma(EP[i + 2][4], PK2(Ks[c][8]), u);
        acc[c][1] += __builtin_elementwise_max(u, vzero);
      }
    }
    __builtin_amdgcn_sched_barrier(0);  // compute may not sink below roll

    // ---- roll in EP-space; expand+pair arrived nv rows ----
    if (j < 6) {
#pragma unroll
      for (int d = 0; d < 5; ++d) { EP[0][d] = EP[4][d]; EP[1][d] = EP[5][d]; }
      if (j == 5 && s == 7) nv[3] = make_float4(0.f, 0.f, 0.f, 0.f);  // row 224
#pragma unroll
      for (int k = 0; k < 4; ++k) {
        float R[6];
        expand(nv[k], R);
        mkpairs(R, EP[2 + k]);
      }
    }
  }

  float acc0 = acc[0][0].x + acc[0][0].y + acc[0][1].x + acc[0][1].y;
  float acc1 = acc[1][0].x + acc[1][0].y + acc[1][1].x + acc[1][1].y;
  float acc2 = acc[2][0].x + acc[2][0].y + acc[2][1].x + acc[2][1].y;
  float acc3 = acc[3][0].x + acc[3][0].y + acc[3][1].x + acc[3][1].y;

  // lanes 56..63 computed lane55's duplicate columns: zero before reduction
  if (lane >= 56) { acc0 = 0.f; acc1 = 0.f; acc2 = 0.f; acc3 = 0.f; }

  // wave-level reduce; one partial per WAVE (no LDS, no barrier)
#pragma unroll
  for (int off = 32; off > 0; off >>= 1) {
    acc0 += __shfl_down(acc0, off);
    acc1 += __shfl_down(acc1, off);
    acc2 += __shfl_down(acc2, off);
    acc3 += __shfl_down(acc3, off);
  }
  if (lane == 0) {
    *reinterpret_cast<float4*>(part + (size_t)W * 4) =
        make_float4(acc0, acc1, acc2, acc3);
  }
}

// ---------------- Kernel 2a: 4-qubit circuit (1 element per lane) ----------------
__device__ __forceinline__ void ry_sc(float (&sr)[16], float (&si)[16],
                                      float s, float c, int M) {
#pragma unroll
  for (int i = 0; i < 16; ++i) {
    if (!(i & M)) {
      const int j = i | M;
      float r0 = sr[i], q0 = si[i], r1 = sr[j], q1 = si[j];
      sr[i] = c * r0 - s * r1;  si[i] = c * q0 - s * q1;
      sr[j] = s * r0 + c * r1;  si[j] = s * q0 + c * q1;
    }
  }
}

__device__ __forceinline__ void rz_sc(float (&sr)[16], float (&si)[16],
                                      float s, float c, int M) {
#pragma unroll
  for (int i = 0; i < 16; ++i) {
    float a = sr[i], q = si[i];
    if (i & M) { sr[i] = a * c - q * s;  si[i] = q * c + a * s; }
    else       { sr[i] = a * c + q * s;  si[i] = q * c - a * s; }
  }
}

__device__ __forceinline__ void cnot_g(float (&sr)[16], float (&si)[16],
                                       int MC, int MT) {
#pragma unroll
  for (int i = 0; i < 16; ++i) {
    if ((i & MC) && !(i & MT)) {
      const int j = i | MT;
      float tr = sr[i]; sr[i] = sr[j]; sr[j] = tr;
      float ti = si[i]; si[i] = si[j]; si[j] = ti;
    }
  }
}

__global__ __launch_bounds__(64) void circuit_k(
    const float* __restrict__ part, const float* __restrict__ params,
    float* __restrict__ ev_out)
{
  const int tid = threadIdx.x;
  const int e = blockIdx.x * 64 + tid;   // batch element

  __shared__ float scs[24], scc[24];     // sin/cos of 0.5*param[i]
  if (tid < 24) {
    float s, c;
    sincosf(0.5f * params[tid], &s, &c);
    scs[tid] = s; scc[tid] = c;
  }
  __syncthreads();

  float4 fs = make_float4(0.f, 0.f, 0.f, 0.f);
#pragma unroll
  for (int s8 = 0; s8 < GROUPS; ++s8) {
    const float4 q = *reinterpret_cast<const float4*>(&part[(e * GROUPS + s8) * 4]);
    fs.x += q.x; fs.y += q.y; fs.z += q.z; fs.w += q.w;
  }
  const float f[4] = { fs.x * (1.0f / NPIX), fs.y * (1.0f / NPIX),
                       fs.z * (1.0f / NPIX), fs.w * (1.0f / NPIX) };

  float sr[16], si[16];
#pragma unroll
  for (int i = 0; i < 16; ++i) { sr[i] = 0.f; si[i] = 0.f; }
  sr[0] = 1.f;

#pragma unroll
  for (int w = 0; w < 4; ++w) {
    float s, c;
    sincosf(0.5f * f[w], &s, &c);
    ry_sc(sr, si, s, c, 8 >> w);
  }

#pragma unroll
  for (int l = 0; l < NL; ++l) {
#pragma unroll
    for (int w = 0; w < 4; ++w) {
      const int idx = l * 8 + w * 2;
      ry_sc(sr, si, scs[idx],     scc[idx],     8 >> w);
      rz_sc(sr, si, scs[idx + 1], scc[idx + 1], 8 >> w);
    }
    cnot_g(sr, si, 8, 4);
    cnot_g(sr, si, 4, 2);
    cnot_g(sr, si, 2, 1);
  }

  float p[16];
#pragma unroll
  for (int i = 0; i < 16; ++i) p[i] = sr[i] * sr[i] + si[i] * si[i];

#pragma unroll
  for (int w = 0; w < 4; ++w) {
    const int m = 8 >> w;
    float ssum = 0.f;
#pragma unroll
    for (int i = 0; i < 16; ++i) ssum += (i & m) ? -p[i] : p[i];
    ev_out[e * 4 + w] = ssum;
  }
}

// ---------------- Kernel 2b: BatchNorm over batch (deterministic) ----------------
__global__ __launch_bounds__(512) void bn_k(
    const float* __restrict__ ev_in, const float* __restrict__ gamma,
    const float* __restrict__ beta, float* __restrict__ out)
{
  const int b = threadIdx.x;   // batch element
  const float4 e4 = *reinterpret_cast<const float4*>(&ev_in[b * 4]);
  float ev[4] = { e4.x, e4.y, e4.z, e4.w };

  float sum[4], sq[4];
#pragma unroll
  for (int w = 0; w < 4; ++w) { sum[w] = ev[w]; sq[w] = ev[w] * ev[w]; }
#pragma unroll
  for (int off = 32; off > 0; off >>= 1) {
#pragma unroll
    for (int w = 0; w < 4; ++w) {
      sum[w] += __shfl_down(sum[w], off);
      sq[w]  += __shfl_down(sq[w],  off);
    }
  }
  __shared__ float psum[8][4], psq[8][4];
  __shared__ float mean_s[4], rstd_s[4];
  const int wave = b >> 6;
  const int lane = b & 63;
  if (lane == 0) {
#pragma unroll
    for (int w = 0; w < 4; ++w) { psum[wave][w] = sum[w]; psq[wave][w] = sq[w]; }
  }
  __syncthreads();
  if (b < 4) {
    float ssum = 0.f, q = 0.f;
#pragma unroll
    for (int wv = 0; wv < 8; ++wv) { ssum += psum[wv][b]; q += psq[wv][b]; }
    const float m = ssum * (1.0f / BATCH);
    const float v = q * (1.0f / BATCH) - m * m;
    mean_s[b] = m;
    rstd_s[b] = rsqrtf(v + EPSV);
  }
  __syncthreads();
#pragma unroll
  for (int w = 0; w < 4; ++w) {
    out[b * 4 + w] = gamma[w] * (ev[w] - mean_s[w]) * rstd_s[w] + beta[w];
  }
}

extern "C" void kernel_launch(void* const* d_in, const int* in_sizes, int n_in,
                              void* d_out, int out_size, void* d_ws, size_t ws_size,
                              hipStream_t stream) {
  const float* x      = (const float*)d_in[0];
  const float* cw     = (const float*)d_in[1];
  const float* params = (const float*)d_in[2];
  const float* gamma  = (const float*)d_in[3];
  const float* beta   = (const float*)d_in[4];
  float* out  = (float*)d_out;
  float* part = (float*)d_ws;                       // 4096 waves * 4 f32 (64 KB)
  float* ev   = (float*)d_ws + BATCH * GROUPS * 4;  // 512 * 4 f32 (8 KB)

  const int B = in_sizes[0] / NPIX;  // 512

  conv_pool_k<<<B * GROUPS / 4, 256, 0, stream>>>(x, cw, part);
  circuit_k<<<BATCH / 64, 64, 0, stream>>>(part, params, ev);
  bn_k<<<1, 512, 0, stream>>>(ev, gamma, beta, out);
}